// Round 6
// baseline (575.903 us; speedup 1.0000x reference)
//
#include <hip/hip_runtime.h>

#define EPS 1e-5f

typedef __attribute__((ext_vector_type(8))) short bf16x8;
typedef __attribute__((ext_vector_type(4))) float f32x4;

// Split f32 -> bf16 hi (truncated) + bf16 lo (residual, truncated).
static __device__ __forceinline__ void split8(float4 f0, float4 f1, bf16x8& hi, bf16x8& lo) {
    float f[8] = {f0.x, f0.y, f0.z, f0.w, f1.x, f1.y, f1.z, f1.w};
    bf16x8 h, l;
#pragma unroll
    for (int i = 0; i < 8; ++i) {
        unsigned u = __float_as_uint(f[i]);
        h[i] = (short)(u >> 16);
        float r = f[i] - __uint_as_float(u & 0xffff0000u);
        l[i] = (short)(__float_as_uint(r) >> 16);
    }
    hi = h; lo = l;
}

// ================= CSR build =================
__global__ __launch_bounds__(256) void hist_kernel(
    const int* __restrict__ ei, int* __restrict__ deg, int E)
{
    int e = blockIdx.x * 256 + threadIdx.x;
    if (e >= E) return;
    atomicAdd(&deg[ei[E + e]], 1);
}

__global__ __launch_bounds__(256) void blocksum_kernel(
    const int* __restrict__ deg, int* __restrict__ bsum, int N)
{
    int i = blockIdx.x * 256 + threadIdx.x;
    int v = (i < N) ? deg[i] : 0;
#pragma unroll
    for (int o = 1; o < 64; o <<= 1) v += __shfl_xor(v, o);
    __shared__ int s[4];
    if ((threadIdx.x & 63) == 0) s[threadIdx.x >> 6] = v;
    __syncthreads();
    if (threadIdx.x == 0) bsum[blockIdx.x] = s[0] + s[1] + s[2] + s[3];
}

__global__ __launch_bounds__(512) void scanb_kernel(int* bsum, int NB)
{
    __shared__ int sh[512];
    int t = threadIdx.x;
    int v = (t < NB) ? bsum[t] : 0;
    sh[t] = v;
    __syncthreads();
    for (int o = 1; o < 512; o <<= 1) {
        int add = (t >= o) ? sh[t - o] : 0;
        __syncthreads();
        sh[t] += add;
        __syncthreads();
    }
    if (t < NB) bsum[t] = (t == 0) ? 0 : sh[t - 1];
}

__global__ __launch_bounds__(256) void scanfinal_kernel(
    const int* __restrict__ deg, const int* __restrict__ bsum,
    int* __restrict__ rowptr, int* __restrict__ cursor, int N)
{
    int b = blockIdx.x, t = threadIdx.x;
    int i = b * 256 + t;
    int v = (i < N) ? deg[i] : 0;
    __shared__ int sh[256];
    sh[t] = v;
    __syncthreads();
    for (int o = 1; o < 256; o <<= 1) {
        int add = (t >= o) ? sh[t - o] : 0;
        __syncthreads();
        sh[t] += add;
        __syncthreads();
    }
    int excl = sh[t] - v;
    if (i < N) {
        int rp = bsum[b] + excl;
        rowptr[i] = rp;
        cursor[i] = rp;
        if (i == N - 1) rowptr[N] = rp + v;
    }
}

__global__ __launch_bounds__(256) void fill_kernel(
    const int* __restrict__ ei, int* __restrict__ cursor, int* __restrict__ col, int E)
{
    int e = blockIdx.x * 256 + threadIdx.x;
    if (e >= E) return;
    int d = ei[E + e];
    int pos = atomicAdd(&cursor[d], 1);
    col[pos] = ei[e];
}

// ================= CSR gather =================
__global__ __launch_bounds__(256) void gather_kernel(
    const float* __restrict__ feat, float* __restrict__ agg,
    const int* __restrict__ rowptr, const int* __restrict__ col, int N)
{
    int gid = blockIdx.x * 256 + threadIdx.x;
    int n = gid >> 5;
    if (n >= N) return;
    int l = gid & 31;
    int beg = rowptr[n], end = rowptr[n + 1];
    float a0x = 0.f, a0y = 0.f, a0z = 0.f, a0w = 0.f;
    float a1x = 0.f, a1y = 0.f, a1z = 0.f, a1w = 0.f;
    int e = beg;
    for (; e + 2 <= end; e += 2) {
        int s0 = col[e], s1 = col[e + 1];
        float4 v0 = *(const float4*)(feat + (size_t)s0 * 128 + l * 4);
        float4 v1 = *(const float4*)(feat + (size_t)s1 * 128 + l * 4);
        a0x += v0.x; a0y += v0.y; a0z += v0.z; a0w += v0.w;
        a1x += v1.x; a1y += v1.y; a1z += v1.z; a1w += v1.w;
    }
    if (e < end) {
        int s0 = col[e];
        float4 v0 = *(const float4*)(feat + (size_t)s0 * 128 + l * 4);
        a0x += v0.x; a0y += v0.y; a0z += v0.z; a0w += v0.w;
    }
    *(float4*)(agg + (size_t)n * 128 + l * 4) =
        make_float4(a0x + a1x, a0y + a1y, a0z + a1z, a0w + a1w);
}

// ================= weight prepack: f32 [128][128] -> MFMA B-frag hi/lo bf16 planes =================
__global__ __launch_bounds__(256) void prepack_kernel(
    const float* __restrict__ W0, const float* __restrict__ W1,
    const float* __restrict__ W2, const float* __restrict__ W3,
    const float* __restrict__ W4, const float* __restrict__ W5,
    ushort* __restrict__ hi, ushort* __restrict__ lo)
{
    int m = blockIdx.y;
    const float* W = (m == 0) ? W0 : (m == 1) ? W1 : (m == 2) ? W2
                   : (m == 3) ? W3 : (m == 4) ? W4 : W5;
    int base = m * 16384;
#pragma unroll
    for (int t = 0; t < 8; ++t) {
        int idx = blockIdx.x * 2048 + t * 256 + threadIdx.x;
        int j = idx & 7, l = (idx >> 3) & 63, cf = (idx >> 9) & 7, kb = idx >> 12;
        int k = kb * 32 + (l >> 4) * 8 + j;
        int n = cf * 16 + (l & 15);
        float v = W[k * 128 + n];
        unsigned u = __float_as_uint(v);
        hi[base + idx] = (ushort)(u >> 16);
        float r = v - __uint_as_float(u & 0xffff0000u);
        lo[base + idx] = (ushort)(__float_as_uint(r) >> 16);
    }
}

// ================= MFMA linear: Y = Xa@Wa (+ Xb@Wb) + bias, split-bf16 3-term =================
// Wave tile: 16 rows x 128 cols (acc = 32 VGPR). Block = 4 waves = 64 rows.
// Grid ~1563 blocks -> ~24 waves/CU available (vs 12 at 128-row blocks):
// round-5 was latency-bound with only ~3 waves/SIMD resident; splitting by
// rows (not cols) keeps A traffic (HBM-dominant) unchanged, only duplicates
// L2-hot B reads.
template<int DUAL, int RELU, int STATS>
__global__ __launch_bounds__(256) void mfma_lin_kernel(
    const float* __restrict__ Xa, const float* __restrict__ Xb,
    const ushort* __restrict__ WaHi, const ushort* __restrict__ WaLo,
    const ushort* __restrict__ WbHi, const ushort* __restrict__ WbLo,
    const float* __restrict__ bias, float* __restrict__ Y,
    float* __restrict__ st, int nrows)
{
    __shared__ float sSum[128], sSq[128];
    if (STATS) {
        if (threadIdx.x < 128) sSum[threadIdx.x] = 0.f;
        else                   sSq[threadIdx.x - 128] = 0.f;
        __syncthreads();
    }
    const int lane = threadIdx.x & 63;
    const int wid  = threadIdx.x >> 6;
    const int q = lane >> 4, s = lane & 15;
    const int rbase = blockIdx.x * 64 + wid * 16;

    f32x4 acc[8];
#pragma unroll
    for (int cf = 0; cf < 8; ++cf)
        acc[cf] = (f32x4){0.f, 0.f, 0.f, 0.f};

    const float4 z4 = make_float4(0.f, 0.f, 0.f, 0.f);

#pragma unroll
    for (int kb = 0; kb < 4; ++kb) {
        bf16x8 ah[2], al[2];   // [op]
        {
            int r = rbase + s;
            bool ok = (r < nrows);
            const float* pa = Xa + (size_t)r * 128 + kb * 32 + q * 8;
            float4 f0 = ok ? *(const float4*)pa : z4;
            float4 f1 = ok ? *(const float4*)(pa + 4) : z4;
            split8(f0, f1, ah[0], al[0]);
            if (DUAL) {
                const float* pb = Xb + (size_t)r * 128 + kb * 32 + q * 8;
                float4 g0 = ok ? *(const float4*)pb : z4;
                float4 g1 = ok ? *(const float4*)(pb + 4) : z4;
                split8(g0, g1, ah[1], al[1]);
            }
        }
#pragma unroll
        for (int cf = 0; cf < 8; ++cf) {
            int boff = ((kb * 8 + cf) * 64 + lane) * 8;
            bf16x8 bh = *(const bf16x8*)(WaHi + boff);
            bf16x8 bl = *(const bf16x8*)(WaLo + boff);
            acc[cf] = __builtin_amdgcn_mfma_f32_16x16x32_bf16(ah[0], bh, acc[cf], 0, 0, 0);
            acc[cf] = __builtin_amdgcn_mfma_f32_16x16x32_bf16(al[0], bh, acc[cf], 0, 0, 0);
            acc[cf] = __builtin_amdgcn_mfma_f32_16x16x32_bf16(ah[0], bl, acc[cf], 0, 0, 0);
            if (DUAL) {
                bf16x8 ch = *(const bf16x8*)(WbHi + boff);
                bf16x8 cl = *(const bf16x8*)(WbLo + boff);
                acc[cf] = __builtin_amdgcn_mfma_f32_16x16x32_bf16(ah[1], ch, acc[cf], 0, 0, 0);
                acc[cf] = __builtin_amdgcn_mfma_f32_16x16x32_bf16(al[1], ch, acc[cf], 0, 0, 0);
                acc[cf] = __builtin_amdgcn_mfma_f32_16x16x32_bf16(ah[1], cl, acc[cf], 0, 0, 0);
            }
        }
    }

    // epilogue: bias (+relu) + store + fused column stats
#pragma unroll
    for (int cf = 0; cf < 8; ++cf) {
        int colc = cf * 16 + s;
        float bv = bias[colc];
        float cs = 0.f, cq = 0.f;
        int r0 = rbase + q * 4;
#pragma unroll
        for (int i = 0; i < 4; ++i) {
            int r = r0 + i;
            float y = acc[cf][i] + bv;
            if (RELU) y = fmaxf(y, 0.f);
            if (r < nrows) {
                Y[(size_t)r * 128 + colc] = y;
                if (STATS) { cs += y; cq += y * y; }
            }
        }
        if (STATS) {
            cs += __shfl_xor(cs, 16); cs += __shfl_xor(cs, 32);
            cq += __shfl_xor(cq, 16); cq += __shfl_xor(cq, 32);
            if (q == 0) { atomicAdd(&sSum[colc], cs); atomicAdd(&sSq[colc], cq); }
        }
    }
    if (STATS) {
        __syncthreads();
        if (threadIdx.x < 128)      atomicAdd(&st[threadIdx.x], sSum[threadIdx.x]);
        else if (threadIdx.x < 256) atomicAdd(&st[threadIdx.x], sSq[threadIdx.x - 128]);
    }
}

// ================= BN finalize =================
__global__ void finalize_kernel(float* st, float inv_n) {
    int c = threadIdx.x;
    float mu = st[c] * inv_n;
    float var = st[128 + c] * inv_n - mu * mu;
    st[256 + c] = mu;
    st[384 + c] = rsqrtf(var + EPS);
}

// ================= BN normalize + ReLU (in place) =================
__global__ __launch_bounds__(256) void bnrelu_kernel(
    float* __restrict__ H, const float* __restrict__ st,
    const float* __restrict__ gamma, const float* __restrict__ beta, int n4)
{
    for (int i = blockIdx.x * 256 + threadIdx.x; i < n4; i += gridDim.x * 256) {
        int c4 = i & 31;
        float4 h = ((float4*)H)[i];
        float4 mu = *(const float4*)(st + 256 + c4 * 4);
        float4 rs = *(const float4*)(st + 384 + c4 * 4);
        float4 g  = *(const float4*)(gamma + c4 * 4);
        float4 b  = *(const float4*)(beta + c4 * 4);
        h.x = fmaxf((h.x - mu.x) * rs.x * g.x + b.x, 0.f);
        h.y = fmaxf((h.y - mu.y) * rs.y * g.y + b.y, 0.f);
        h.z = fmaxf((h.z - mu.z) * rs.z * g.z + b.z, 0.f);
        h.w = fmaxf((h.w - mu.w) * rs.w * g.w + b.w, 0.f);
        ((float4*)H)[i] = h;
    }
}

// ================= final projection to DOUT=2 =================
__global__ __launch_bounds__(256) void linout_kernel(
    const float* __restrict__ X, const float* __restrict__ W, const float* __restrict__ b,
    float* __restrict__ out, int nrows)
{
    int r = blockIdx.x * 256 + threadIdx.x;
    if (r >= nrows) return;
    float a0 = 0.f, a1 = 0.f;
    const float* xr = X + (size_t)r * 128;
#pragma unroll 8
    for (int k = 0; k < 128; k += 4) {
        float4 x = *(const float4*)(xr + k);
        a0 += x.x * W[(k + 0) * 2]     + x.y * W[(k + 1) * 2]
            + x.z * W[(k + 2) * 2]     + x.w * W[(k + 3) * 2];
        a1 += x.x * W[(k + 0) * 2 + 1] + x.y * W[(k + 1) * 2 + 1]
            + x.z * W[(k + 2) * 2 + 1] + x.w * W[(k + 3) * 2 + 1];
    }
    float2 o = make_float2(a0 + b[0], a1 + b[1]);
    *(float2*)(out + (size_t)r * 2) = o;
}

extern "C" void kernel_launch(void* const* d_in, const int* in_sizes, int n_in,
                              void* d_out, int out_size, void* d_ws, size_t ws_size,
                              hipStream_t stream) {
    const float* x   = (const float*)d_in[0];
    const int*   ei  = (const int*)d_in[1];
    const float* Wl0 = (const float*)d_in[2];
    const float* bl0 = (const float*)d_in[3];
    const float* Wr0 = (const float*)d_in[4];
    const float* Wl1 = (const float*)d_in[5];
    const float* bl1 = (const float*)d_in[6];
    const float* Wr1 = (const float*)d_in[7];
    const float* g0  = (const float*)d_in[8];
    const float* be0 = (const float*)d_in[9];
    const float* g1  = (const float*)d_in[10];
    const float* be1 = (const float*)d_in[11];
    const float* W1  = (const float*)d_in[12];
    const float* b1  = (const float*)d_in[13];
    const float* W2  = (const float*)d_in[14];
    const float* b2  = (const float*)d_in[15];
    const float* W3  = (const float*)d_in[16];
    const float* b3  = (const float*)d_in[17];
    float* out = (float*)d_out;

    const int N = in_sizes[0] / 128;
    const int E = in_sizes[1] / 2;

    // workspace layout
    float* A  = (float*)d_ws;                    // [N,128]
    float* B  = A + (size_t)N * 128;             // [N,128]
    float* st = B + (size_t)N * 128;             // 512 floats
    ushort* wHi = (ushort*)(st + 512);           // 6 * 16384
    ushort* wLo = wHi + 6 * 16384;               // 6 * 16384
    int* deg    = (int*)(wLo + 6 * 16384);       // N
    int* rowptr = deg + N;                       // N+1
    int* cursor = rowptr + N + 1;                // N
    int* col    = cursor + N;                    // E
    int* bsum   = col + E;                       // <=512

    const int linGrid    = (N + 63) / 64;
    const int edgeGrid   = (E + 255) / 256;
    const int nodeGrid   = (N + 255) / 256;
    const int gatherGrid = ((size_t)N * 32 + 255) / 256;
    const float inv_n = 1.0f / (float)N;

    // matrix slots: 0=Wl0 1=Wr0 2=Wl1 3=Wr1 4=W1 5=W2
    prepack_kernel<<<dim3(8, 6), 256, 0, stream>>>(Wl0, Wr0, Wl1, Wr1, W1, W2, wHi, wLo);

    // ----- CSR build -----
    hipMemsetAsync(deg, 0, (size_t)N * sizeof(int), stream);
    hist_kernel<<<edgeGrid, 256, 0, stream>>>(ei, deg, E);
    blocksum_kernel<<<nodeGrid, 256, 0, stream>>>(deg, bsum, N);
    scanb_kernel<<<1, 512, 0, stream>>>(bsum, nodeGrid);
    scanfinal_kernel<<<nodeGrid, 256, 0, stream>>>(deg, bsum, rowptr, cursor, N);
    fill_kernel<<<edgeGrid, 256, 0, stream>>>(ei, cursor, col, E);

    // ----- layer 0: h0 = agg(x)@Wl0 + x@Wr0 + bl0, fused stats -----
    gather_kernel<<<gatherGrid, 256, 0, stream>>>(x, A, rowptr, col, N);
    hipMemsetAsync(st, 0, 256 * sizeof(float), stream);
    mfma_lin_kernel<1, 0, 1><<<linGrid, 256, 0, stream>>>(
        A, x, wHi, wLo, wHi + 16384, wLo + 16384, bl0, A, st, N);
    finalize_kernel<<<1, 128, 0, stream>>>(st, inv_n);
    bnrelu_kernel<<<2048, 256, 0, stream>>>(A, st, g0, be0, N * 32);

    // ----- layer 1 -----
    gather_kernel<<<gatherGrid, 256, 0, stream>>>(A, B, rowptr, col, N);
    hipMemsetAsync(st, 0, 256 * sizeof(float), stream);
    mfma_lin_kernel<1, 0, 1><<<linGrid, 256, 0, stream>>>(
        B, A, wHi + 2 * 16384, wLo + 2 * 16384, wHi + 3 * 16384, wLo + 3 * 16384, bl1, B, st, N);
    finalize_kernel<<<1, 128, 0, stream>>>(st, inv_n);
    bnrelu_kernel<<<2048, 256, 0, stream>>>(B, st, g1, be1, N * 32);

    // ----- MLP head -----
    mfma_lin_kernel<0, 1, 0><<<linGrid, 256, 0, stream>>>(
        B, nullptr, wHi + 4 * 16384, wLo + 4 * 16384, nullptr, nullptr, b1, A, nullptr, N);
    mfma_lin_kernel<0, 1, 0><<<linGrid, 256, 0, stream>>>(
        A, nullptr, wHi + 5 * 16384, wLo + 5 * 16384, nullptr, nullptr, b2, B, nullptr, N);
    linout_kernel<<<(N + 255) / 256, 256, 0, stream>>>(B, W3, b3, out, N);
}

// Round 7
// 522.354 us; speedup vs baseline: 1.1025x; 1.1025x over previous
//
#include <hip/hip_runtime.h>

#define EPS 1e-5f

typedef __attribute__((ext_vector_type(8))) short bf16x8;
typedef __attribute__((ext_vector_type(4))) float f32x4;

// Split f32 -> bf16 hi (truncated) + bf16 lo (residual, truncated).
static __device__ __forceinline__ void split8(float4 f0, float4 f1, bf16x8& hi, bf16x8& lo) {
    float f[8] = {f0.x, f0.y, f0.z, f0.w, f1.x, f1.y, f1.z, f1.w};
    bf16x8 h, l;
#pragma unroll
    for (int i = 0; i < 8; ++i) {
        unsigned u = __float_as_uint(f[i]);
        h[i] = (short)(u >> 16);
        float r = f[i] - __uint_as_float(u & 0xffff0000u);
        l[i] = (short)(__float_as_uint(r) >> 16);
    }
    hi = h; lo = l;
}

// ================= CSR build =================
__global__ __launch_bounds__(256) void hist_kernel(
    const int* __restrict__ ei, int* __restrict__ deg, int E)
{
    int e = blockIdx.x * 256 + threadIdx.x;
    if (e >= E) return;
    atomicAdd(&deg[ei[E + e]], 1);
}

__global__ __launch_bounds__(256) void blocksum_kernel(
    const int* __restrict__ deg, int* __restrict__ bsum, int N)
{
    int i = blockIdx.x * 256 + threadIdx.x;
    int v = (i < N) ? deg[i] : 0;
#pragma unroll
    for (int o = 1; o < 64; o <<= 1) v += __shfl_xor(v, o);
    __shared__ int s[4];
    if ((threadIdx.x & 63) == 0) s[threadIdx.x >> 6] = v;
    __syncthreads();
    if (threadIdx.x == 0) bsum[blockIdx.x] = s[0] + s[1] + s[2] + s[3];
}

__global__ __launch_bounds__(512) void scanb_kernel(int* bsum, int NB)
{
    __shared__ int sh[512];
    int t = threadIdx.x;
    int v = (t < NB) ? bsum[t] : 0;
    sh[t] = v;
    __syncthreads();
    for (int o = 1; o < 512; o <<= 1) {
        int add = (t >= o) ? sh[t - o] : 0;
        __syncthreads();
        sh[t] += add;
        __syncthreads();
    }
    if (t < NB) bsum[t] = (t == 0) ? 0 : sh[t - 1];
}

__global__ __launch_bounds__(256) void scanfinal_kernel(
    const int* __restrict__ deg, const int* __restrict__ bsum,
    int* __restrict__ rowptr, int* __restrict__ cursor, int N)
{
    int b = blockIdx.x, t = threadIdx.x;
    int i = b * 256 + t;
    int v = (i < N) ? deg[i] : 0;
    __shared__ int sh[256];
    sh[t] = v;
    __syncthreads();
    for (int o = 1; o < 256; o <<= 1) {
        int add = (t >= o) ? sh[t - o] : 0;
        __syncthreads();
        sh[t] += add;
        __syncthreads();
    }
    int excl = sh[t] - v;
    if (i < N) {
        int rp = bsum[b] + excl;
        rowptr[i] = rp;
        cursor[i] = rp;
        if (i == N - 1) rowptr[N] = rp + v;
    }
}

__global__ __launch_bounds__(256) void fill_kernel(
    const int* __restrict__ ei, int* __restrict__ cursor, int* __restrict__ col, int E)
{
    int e = blockIdx.x * 256 + threadIdx.x;
    if (e >= E) return;
    int d = ei[E + e];
    int pos = atomicAdd(&cursor[d], 1);
    col[pos] = ei[e];
}

// ================= CSR gather =================
__global__ __launch_bounds__(256) void gather_kernel(
    const float* __restrict__ feat, float* __restrict__ agg,
    const int* __restrict__ rowptr, const int* __restrict__ col, int N)
{
    int gid = blockIdx.x * 256 + threadIdx.x;
    int n = gid >> 5;
    if (n >= N) return;
    int l = gid & 31;
    int beg = rowptr[n], end = rowptr[n + 1];
    float a0x = 0.f, a0y = 0.f, a0z = 0.f, a0w = 0.f;
    float a1x = 0.f, a1y = 0.f, a1z = 0.f, a1w = 0.f;
    int e = beg;
    for (; e + 2 <= end; e += 2) {
        int s0 = col[e], s1 = col[e + 1];
        float4 v0 = *(const float4*)(feat + (size_t)s0 * 128 + l * 4);
        float4 v1 = *(const float4*)(feat + (size_t)s1 * 128 + l * 4);
        a0x += v0.x; a0y += v0.y; a0z += v0.z; a0w += v0.w;
        a1x += v1.x; a1y += v1.y; a1z += v1.z; a1w += v1.w;
    }
    if (e < end) {
        int s0 = col[e];
        float4 v0 = *(const float4*)(feat + (size_t)s0 * 128 + l * 4);
        a0x += v0.x; a0y += v0.y; a0z += v0.z; a0w += v0.w;
    }
    *(float4*)(agg + (size_t)n * 128 + l * 4) =
        make_float4(a0x + a1x, a0y + a1y, a0z + a1z, a0w + a1w);
}

// ================= weight prepack: f32 [128][128] -> packed per-matrix [hi|lo] planes =================
// Matrix m occupies wPk[m*32768 .. +32768): first 16384 = hi plane, next 16384 = lo plane.
// Plane layout: [kb][cf][lane][j8]: element W[kb*32 + (lane>>4)*8 + j][cf*16 + (lane&15)],
// so a lane's 8 elements are 16B contiguous.
__global__ __launch_bounds__(256) void prepack_kernel(
    const float* __restrict__ W0, const float* __restrict__ W1,
    const float* __restrict__ W2, const float* __restrict__ W3,
    const float* __restrict__ W4, const float* __restrict__ W5,
    ushort* __restrict__ wPk)
{
    int m = blockIdx.y;
    const float* W = (m == 0) ? W0 : (m == 1) ? W1 : (m == 2) ? W2
                   : (m == 3) ? W3 : (m == 4) ? W4 : W5;
    int base = m * 32768;
#pragma unroll
    for (int t = 0; t < 8; ++t) {
        int idx = blockIdx.x * 2048 + t * 256 + threadIdx.x;
        int j = idx & 7, l = (idx >> 3) & 63, cf = (idx >> 9) & 7, kb = idx >> 12;
        int k = kb * 32 + (l >> 4) * 8 + j;
        int n = cf * 16 + (l & 15);
        float v = W[k * 128 + n];
        unsigned u = __float_as_uint(v);
        wPk[base + idx] = (ushort)(u >> 16);
        float r = v - __uint_as_float(u & 0xffff0000u);
        wPk[base + 16384 + idx] = (ushort)(__float_as_uint(r) >> 16);
    }
}

// ================= MFMA linear: Y = Xa@Wa (+ Xb@Wb) + bias, split-bf16 3-term =================
// Weights staged wholly in LDS (dual: 4 planes = 128KB; single: 2 planes = 64KB),
// so the inner loop is ds_read + MFMA (compiler pipelines these well).
// A streamed via a manual 2-deep register double-buffer (named bufs, rule #20),
// no barriers inside the K-loop -> A-loads issue 2 K-chunks ahead.
struct ABuf { float4 x0[2], x1[2], y0[2], y1[2]; };

template<int DUAL>
static __device__ __forceinline__ void loadA(
    const float* __restrict__ Xa, const float* __restrict__ Xb,
    int rbase, int s, int q, int nrows, int kb, ABuf& b)
{
    const float4 z4 = make_float4(0.f, 0.f, 0.f, 0.f);
#pragma unroll
    for (int rf = 0; rf < 2; ++rf) {
        int r = rbase + rf * 16 + s;
        bool ok = (r < nrows);
        const float* pa = Xa + (size_t)r * 128 + kb * 32 + q * 8;
        b.x0[rf] = ok ? *(const float4*)pa : z4;
        b.x1[rf] = ok ? *(const float4*)(pa + 4) : z4;
        if (DUAL) {
            const float* pb = Xb + (size_t)r * 128 + kb * 32 + q * 8;
            b.y0[rf] = ok ? *(const float4*)pb : z4;
            b.y1[rf] = ok ? *(const float4*)(pb + 4) : z4;
        }
    }
}

template<int DUAL>
static __device__ __forceinline__ void computeK(
    const ushort* sB, int lane, int kb, const ABuf& b, f32x4 (&acc)[2][8])
{
    bf16x8 ah[2], al[2], gh[2], gl[2];
#pragma unroll
    for (int rf = 0; rf < 2; ++rf) {
        split8(b.x0[rf], b.x1[rf], ah[rf], al[rf]);
        if (DUAL) split8(b.y0[rf], b.y1[rf], gh[rf], gl[rf]);
    }
#pragma unroll
    for (int cf = 0; cf < 8; ++cf) {
        int off = ((kb * 8 + cf) * 64 + lane) * 8;
        bf16x8 bh = *(const bf16x8*)(sB + off);
        bf16x8 bl = *(const bf16x8*)(sB + off + 16384);
#pragma unroll
        for (int rf = 0; rf < 2; ++rf) {
            acc[rf][cf] = __builtin_amdgcn_mfma_f32_16x16x32_bf16(ah[rf], bh, acc[rf][cf], 0, 0, 0);
            acc[rf][cf] = __builtin_amdgcn_mfma_f32_16x16x32_bf16(al[rf], bh, acc[rf][cf], 0, 0, 0);
            acc[rf][cf] = __builtin_amdgcn_mfma_f32_16x16x32_bf16(ah[rf], bl, acc[rf][cf], 0, 0, 0);
        }
        if (DUAL) {
            bf16x8 ch = *(const bf16x8*)(sB + off + 32768);
            bf16x8 cl = *(const bf16x8*)(sB + off + 49152);
#pragma unroll
            for (int rf = 0; rf < 2; ++rf) {
                acc[rf][cf] = __builtin_amdgcn_mfma_f32_16x16x32_bf16(gh[rf], ch, acc[rf][cf], 0, 0, 0);
                acc[rf][cf] = __builtin_amdgcn_mfma_f32_16x16x32_bf16(gl[rf], ch, acc[rf][cf], 0, 0, 0);
                acc[rf][cf] = __builtin_amdgcn_mfma_f32_16x16x32_bf16(gh[rf], cl, acc[rf][cf], 0, 0, 0);
            }
        }
    }
}

template<int DUAL, int RELU, int STATS>
__global__ __launch_bounds__(512, 2) void mfma_lin_kernel(
    const float* __restrict__ Xa, const float* __restrict__ Xb,
    const ushort* __restrict__ WaPk, const ushort* __restrict__ WbPk,
    const float* __restrict__ bias, float* __restrict__ Y,
    float* __restrict__ st, int nrows)
{
    extern __shared__ ushort sB[];
    __shared__ float sSum[128], sSq[128];
    const int tid = threadIdx.x;
    if (STATS) {
        if (tid < 128)      sSum[tid] = 0.f;
        else if (tid < 256) sSq[tid - 128] = 0.f;
    }

    // stage weight planes into LDS (linear copy of prepacked layout)
    {
        const int nchunk = DUAL ? 8192 : 4096;   // 16B chunks
        for (int c = tid; c < nchunk; c += 512) {
            const ushort* src = (DUAL && c >= 4096) ? (WbPk + (size_t)(c - 4096) * 8)
                                                    : (WaPk + (size_t)c * 8);
            *(bf16x8*)(sB + (size_t)c * 8) = *(const bf16x8*)src;
        }
    }

    const int lane = tid & 63;
    const int wid  = tid >> 6;
    const int q = lane >> 4, s = lane & 15;
    const int rbase = blockIdx.x * 256 + wid * 32;

    f32x4 acc[2][8];
#pragma unroll
    for (int rf = 0; rf < 2; ++rf)
#pragma unroll
        for (int cf = 0; cf < 8; ++cf)
            acc[rf][cf] = (f32x4){0.f, 0.f, 0.f, 0.f};

    ABuf bufA, bufB;
    loadA<DUAL>(Xa, Xb, rbase, s, q, nrows, 0, bufA);   // issue before barrier:
    loadA<DUAL>(Xa, Xb, rbase, s, q, nrows, 1, bufB);   // HBM latency hides under staging
    __syncthreads();

    computeK<DUAL>(sB, lane, 0, bufA, acc);
    loadA<DUAL>(Xa, Xb, rbase, s, q, nrows, 2, bufA);
    computeK<DUAL>(sB, lane, 1, bufB, acc);
    loadA<DUAL>(Xa, Xb, rbase, s, q, nrows, 3, bufB);
    computeK<DUAL>(sB, lane, 2, bufA, acc);
    computeK<DUAL>(sB, lane, 3, bufB, acc);

    // epilogue: bias (+relu) + store + fused column stats
#pragma unroll
    for (int cf = 0; cf < 8; ++cf) {
        int colc = cf * 16 + s;
        float bv = bias[colc];
        float cs = 0.f, cq = 0.f;
#pragma unroll
        for (int rf = 0; rf < 2; ++rf) {
            int r0 = rbase + rf * 16 + q * 4;
#pragma unroll
            for (int i = 0; i < 4; ++i) {
                int r = r0 + i;
                float y = acc[rf][cf][i] + bv;
                if (RELU) y = fmaxf(y, 0.f);
                if (r < nrows) {
                    Y[(size_t)r * 128 + colc] = y;
                    if (STATS) { cs += y; cq += y * y; }
                }
            }
        }
        if (STATS) {
            cs += __shfl_xor(cs, 16); cs += __shfl_xor(cs, 32);
            cq += __shfl_xor(cq, 16); cq += __shfl_xor(cq, 32);
            if (q == 0) { atomicAdd(&sSum[colc], cs); atomicAdd(&sSq[colc], cq); }
        }
    }
    if (STATS) {
        __syncthreads();
        if (tid < 128)      atomicAdd(&st[tid], sSum[tid]);
        else if (tid < 256) atomicAdd(&st[tid], sSq[tid - 128]);
    }
}

// ================= BN finalize =================
__global__ void finalize_kernel(float* st, float inv_n) {
    int c = threadIdx.x;
    float mu = st[c] * inv_n;
    float var = st[128 + c] * inv_n - mu * mu;
    st[256 + c] = mu;
    st[384 + c] = rsqrtf(var + EPS);
}

// ================= BN normalize + ReLU (in place) =================
__global__ __launch_bounds__(256) void bnrelu_kernel(
    float* __restrict__ H, const float* __restrict__ st,
    const float* __restrict__ gamma, const float* __restrict__ beta, int n4)
{
    for (int i = blockIdx.x * 256 + threadIdx.x; i < n4; i += gridDim.x * 256) {
        int c4 = i & 31;
        float4 h = ((float4*)H)[i];
        float4 mu = *(const float4*)(st + 256 + c4 * 4);
        float4 rs = *(const float4*)(st + 384 + c4 * 4);
        float4 g  = *(const float4*)(gamma + c4 * 4);
        float4 b  = *(const float4*)(beta + c4 * 4);
        h.x = fmaxf((h.x - mu.x) * rs.x * g.x + b.x, 0.f);
        h.y = fmaxf((h.y - mu.y) * rs.y * g.y + b.y, 0.f);
        h.z = fmaxf((h.z - mu.z) * rs.z * g.z + b.z, 0.f);
        h.w = fmaxf((h.w - mu.w) * rs.w * g.w + b.w, 0.f);
        ((float4*)H)[i] = h;
    }
}

// ================= final projection to DOUT=2 =================
__global__ __launch_bounds__(256) void linout_kernel(
    const float* __restrict__ X, const float* __restrict__ W, const float* __restrict__ b,
    float* __restrict__ out, int nrows)
{
    int r = blockIdx.x * 256 + threadIdx.x;
    if (r >= nrows) return;
    float a0 = 0.f, a1 = 0.f;
    const float* xr = X + (size_t)r * 128;
#pragma unroll 8
    for (int k = 0; k < 128; k += 4) {
        float4 x = *(const float4*)(xr + k);
        a0 += x.x * W[(k + 0) * 2]     + x.y * W[(k + 1) * 2]
            + x.z * W[(k + 2) * 2]     + x.w * W[(k + 3) * 2];
        a1 += x.x * W[(k + 0) * 2 + 1] + x.y * W[(k + 1) * 2 + 1]
            + x.z * W[(k + 2) * 2 + 1] + x.w * W[(k + 3) * 2 + 1];
    }
    float2 o = make_float2(a0 + b[0], a1 + b[1]);
    *(float2*)(out + (size_t)r * 2) = o;
}

extern "C" void kernel_launch(void* const* d_in, const int* in_sizes, int n_in,
                              void* d_out, int out_size, void* d_ws, size_t ws_size,
                              hipStream_t stream) {
    const float* x   = (const float*)d_in[0];
    const int*   ei  = (const int*)d_in[1];
    const float* Wl0 = (const float*)d_in[2];
    const float* bl0 = (const float*)d_in[3];
    const float* Wr0 = (const float*)d_in[4];
    const float* Wl1 = (const float*)d_in[5];
    const float* bl1 = (const float*)d_in[6];
    const float* Wr1 = (const float*)d_in[7];
    const float* g0  = (const float*)d_in[8];
    const float* be0 = (const float*)d_in[9];
    const float* g1  = (const float*)d_in[10];
    const float* be1 = (const float*)d_in[11];
    const float* W1  = (const float*)d_in[12];
    const float* b1  = (const float*)d_in[13];
    const float* W2  = (const float*)d_in[14];
    const float* b2  = (const float*)d_in[15];
    const float* W3  = (const float*)d_in[16];
    const float* b3  = (const float*)d_in[17];
    float* out = (float*)d_out;

    const int N = in_sizes[0] / 128;
    const int E = in_sizes[1] / 2;

    // workspace layout
    float* A  = (float*)d_ws;                    // [N,128]
    float* B  = A + (size_t)N * 128;             // [N,128]
    float* st = B + (size_t)N * 128;             // 512 floats
    ushort* wPk = (ushort*)(st + 512);           // 6 * 32768 (per-matrix [hi|lo])
    int* deg    = (int*)(wPk + 6 * 32768);       // N
    int* rowptr = deg + N;                       // N+1
    int* cursor = rowptr + N + 1;                // N
    int* col    = cursor + N;                    // E
    int* bsum   = col + E;                       // <=512

    const int linGrid    = (N + 255) / 256;
    const int edgeGrid   = (E + 255) / 256;
    const int nodeGrid   = (N + 255) / 256;
    const int gatherGrid = ((size_t)N * 32 + 255) / 256;
    const float inv_n = 1.0f / (float)N;
    const size_t shDual = 4 * 32768;   // 128 KB
    const size_t shSing = 2 * 32768;   // 64 KB

    // matrix slots: 0=Wl0 1=Wr0 2=Wl1 3=Wr1 4=W1 5=W2
    prepack_kernel<<<dim3(8, 6), 256, 0, stream>>>(Wl0, Wr0, Wl1, Wr1, W1, W2, wPk);

    // ----- CSR build -----
    hipMemsetAsync(deg, 0, (size_t)N * sizeof(int), stream);
    hist_kernel<<<edgeGrid, 256, 0, stream>>>(ei, deg, E);
    blocksum_kernel<<<nodeGrid, 256, 0, stream>>>(deg, bsum, N);
    scanb_kernel<<<1, 512, 0, stream>>>(bsum, nodeGrid);
    scanfinal_kernel<<<nodeGrid, 256, 0, stream>>>(deg, bsum, rowptr, cursor, N);
    fill_kernel<<<edgeGrid, 256, 0, stream>>>(ei, cursor, col, E);

    // ----- layer 0: h0 = agg(x)@Wl0 + x@Wr0 + bl0, fused stats -----
    gather_kernel<<<gatherGrid, 256, 0, stream>>>(x, A, rowptr, col, N);
    hipMemsetAsync(st, 0, 256 * sizeof(float), stream);
    mfma_lin_kernel<1, 0, 1><<<linGrid, 512, shDual, stream>>>(
        A, x, wPk, wPk + 32768, bl0, A, st, N);
    finalize_kernel<<<1, 128, 0, stream>>>(st, inv_n);
    bnrelu_kernel<<<2048, 256, 0, stream>>>(A, st, g0, be0, N * 32);

    // ----- layer 1 -----
    gather_kernel<<<gatherGrid, 256, 0, stream>>>(A, B, rowptr, col, N);
    hipMemsetAsync(st, 0, 256 * sizeof(float), stream);
    mfma_lin_kernel<1, 0, 1><<<linGrid, 512, shDual, stream>>>(
        B, A, wPk + 2 * 32768, wPk + 3 * 32768, bl1, B, st, N);
    finalize_kernel<<<1, 128, 0, stream>>>(st, inv_n);
    bnrelu_kernel<<<2048, 256, 0, stream>>>(B, st, g1, be1, N * 32);

    // ----- MLP head -----
    mfma_lin_kernel<0, 1, 0><<<linGrid, 512, shSing, stream>>>(
        B, nullptr, wPk + 4 * 32768, nullptr, b1, A, nullptr, N);
    mfma_lin_kernel<0, 1, 0><<<linGrid, 512, shSing, stream>>>(
        A, nullptr, wPk + 5 * 32768, nullptr, b2, B, nullptr, N);
    linout_kernel<<<(N + 255) / 256, 256, 0, stream>>>(B, W3, b3, out, N);
}

// Round 8
// 436.914 us; speedup vs baseline: 1.3181x; 1.1956x over previous
//
#include <hip/hip_runtime.h>

#define EPS 1e-5f

typedef __attribute__((ext_vector_type(8))) short bf16x8;
typedef __attribute__((ext_vector_type(4))) float f32x4;

#define GLOBAL_LOAD_LDS16(gp, lp) \
    __builtin_amdgcn_global_load_lds((const __attribute__((address_space(1))) unsigned int*)(gp), \
                                     (__attribute__((address_space(3))) unsigned int*)(lp), 16, 0, 0)

// Split f32 -> bf16 hi (truncated) + bf16 lo (residual, truncated).
static __device__ __forceinline__ void split8(float4 f0, float4 f1, bf16x8& hi, bf16x8& lo) {
    float f[8] = {f0.x, f0.y, f0.z, f0.w, f1.x, f1.y, f1.z, f1.w};
    bf16x8 h, l;
#pragma unroll
    for (int i = 0; i < 8; ++i) {
        unsigned u = __float_as_uint(f[i]);
        h[i] = (short)(u >> 16);
        float r = f[i] - __uint_as_float(u & 0xffff0000u);
        l[i] = (short)(__float_as_uint(r) >> 16);
    }
    hi = h; lo = l;
}

// ================= CSR build =================
__global__ __launch_bounds__(256) void hist_kernel(
    const int* __restrict__ ei, int* __restrict__ deg, int E)
{
    int e = blockIdx.x * 256 + threadIdx.x;
    if (e >= E) return;
    atomicAdd(&deg[ei[E + e]], 1);
}

__global__ __launch_bounds__(256) void blocksum_kernel(
    const int* __restrict__ deg, int* __restrict__ bsum, int N)
{
    int i = blockIdx.x * 256 + threadIdx.x;
    int v = (i < N) ? deg[i] : 0;
#pragma unroll
    for (int o = 1; o < 64; o <<= 1) v += __shfl_xor(v, o);
    __shared__ int s[4];
    if ((threadIdx.x & 63) == 0) s[threadIdx.x >> 6] = v;
    __syncthreads();
    if (threadIdx.x == 0) bsum[blockIdx.x] = s[0] + s[1] + s[2] + s[3];
}

__global__ __launch_bounds__(512) void scanb_kernel(int* bsum, int NB)
{
    __shared__ int sh[512];
    int t = threadIdx.x;
    int v = (t < NB) ? bsum[t] : 0;
    sh[t] = v;
    __syncthreads();
    for (int o = 1; o < 512; o <<= 1) {
        int add = (t >= o) ? sh[t - o] : 0;
        __syncthreads();
        sh[t] += add;
        __syncthreads();
    }
    if (t < NB) bsum[t] = (t == 0) ? 0 : sh[t - 1];
}

__global__ __launch_bounds__(256) void scanfinal_kernel(
    const int* __restrict__ deg, const int* __restrict__ bsum,
    int* __restrict__ rowptr, int* __restrict__ cursor, int N)
{
    int b = blockIdx.x, t = threadIdx.x;
    int i = b * 256 + t;
    int v = (i < N) ? deg[i] : 0;
    __shared__ int sh[256];
    sh[t] = v;
    __syncthreads();
    for (int o = 1; o < 256; o <<= 1) {
        int add = (t >= o) ? sh[t - o] : 0;
        __syncthreads();
        sh[t] += add;
        __syncthreads();
    }
    int excl = sh[t] - v;
    if (i < N) {
        int rp = bsum[b] + excl;
        rowptr[i] = rp;
        cursor[i] = rp;
        if (i == N - 1) rowptr[N] = rp + v;
    }
}

__global__ __launch_bounds__(256) void fill_kernel(
    const int* __restrict__ ei, int* __restrict__ cursor, int* __restrict__ col, int E)
{
    int e = blockIdx.x * 256 + threadIdx.x;
    if (e >= E) return;
    int d = ei[E + e];
    int pos = atomicAdd(&cursor[d], 1);
    col[pos] = ei[e];
}

// ================= CSR gather =================
__global__ __launch_bounds__(256) void gather_kernel(
    const float* __restrict__ feat, float* __restrict__ agg,
    const int* __restrict__ rowptr, const int* __restrict__ col, int N)
{
    int gid = blockIdx.x * 256 + threadIdx.x;
    int n = gid >> 5;
    if (n >= N) return;
    int l = gid & 31;
    int beg = rowptr[n], end = rowptr[n + 1];
    float a0x = 0.f, a0y = 0.f, a0z = 0.f, a0w = 0.f;
    float a1x = 0.f, a1y = 0.f, a1z = 0.f, a1w = 0.f;
    int e = beg;
    for (; e + 2 <= end; e += 2) {
        int s0 = col[e], s1 = col[e + 1];
        float4 v0 = *(const float4*)(feat + (size_t)s0 * 128 + l * 4);
        float4 v1 = *(const float4*)(feat + (size_t)s1 * 128 + l * 4);
        a0x += v0.x; a0y += v0.y; a0z += v0.z; a0w += v0.w;
        a1x += v1.x; a1y += v1.y; a1z += v1.z; a1w += v1.w;
    }
    if (e < end) {
        int s0 = col[e];
        float4 v0 = *(const float4*)(feat + (size_t)s0 * 128 + l * 4);
        a0x += v0.x; a0y += v0.y; a0z += v0.z; a0w += v0.w;
    }
    *(float4*)(agg + (size_t)n * 128 + l * 4) =
        make_float4(a0x + a1x, a0y + a1y, a0z + a1z, a0w + a1w);
}

// ================= weight prepack: f32 [128][128] -> packed per-matrix [hi|lo] planes =================
// Matrix m occupies wPk[m*32768 .. +32768): first 16384 = hi plane, next 16384 = lo plane.
// Plane layout: [kb][cf][lane][j8]: element W[kb*32 + (lane>>4)*8 + j][cf*16 + (lane&15)].
__global__ __launch_bounds__(256) void prepack_kernel(
    const float* __restrict__ W0, const float* __restrict__ W1,
    const float* __restrict__ W2, const float* __restrict__ W3,
    const float* __restrict__ W4, const float* __restrict__ W5,
    ushort* __restrict__ wPk)
{
    int m = blockIdx.y;
    const float* W = (m == 0) ? W0 : (m == 1) ? W1 : (m == 2) ? W2
                   : (m == 3) ? W3 : (m == 4) ? W4 : W5;
    int base = m * 32768;
#pragma unroll
    for (int t = 0; t < 8; ++t) {
        int idx = blockIdx.x * 2048 + t * 256 + threadIdx.x;
        int j = idx & 7, l = (idx >> 3) & 63, cf = (idx >> 9) & 7, kb = idx >> 12;
        int k = kb * 32 + (l >> 4) * 8 + j;
        int n = cf * 16 + (l & 15);
        float v = W[k * 128 + n];
        unsigned u = __float_as_uint(v);
        wPk[base + idx] = (ushort)(u >> 16);
        float r = v - __uint_as_float(u & 0xffff0000u);
        wPk[base + 16384 + idx] = (ushort)(__float_as_uint(r) >> 16);
    }
}

// ================= MFMA linear: Y = Xa@Wa (+ Xb@Wb) + bias, split-bf16 3-term =================
// A staged global->LDS via global_load_lds width=16 with COALESCED per-lane sources
// (8 lanes x 16B = one row's 128B k-slice; wave covers 8 rows/instr), double-buffered
// over the 4 K-chunks. XOR source-swizzle (unit ^= row&7) + matching swizzled ds_read
// (rule #21 both-sides involution) -> fragment reads hit the 8-pass b128 floor.
// Weights from global (prepacked, 1KB/instr coalesced, L2-hot).

template<int DUAL>
static __device__ __forceinline__ void stageA(
    const float* __restrict__ Xa, const float* __restrict__ Xb,
    float* sbuf, int rbase0, int wid, int lane, int nrows, int kb)
{
    const int rl8 = lane >> 3;                 // 0..7: row within 8-row group
    const int c   = lane & 7;                  // 16B unit within row
#pragma unroll
    for (int u = 0; u < 4; ++u) {
        int row_local = wid * 32 + u * 8 + rl8;
        int gr = rbase0 + row_local;
        if (gr > nrows - 1) gr = nrows - 1;    // clamp: no OOB reads, stores masked later
        int xu = c ^ (row_local & 7);          // pre-swizzled source unit
        const float* ga = Xa + (size_t)gr * 128 + kb * 32 + xu * 4;
        float* la = sbuf + (size_t)(wid * 32 + u * 8) * 32;   // wave-uniform LDS base
        GLOBAL_LOAD_LDS16(ga, la);
        if (DUAL) {
            const float* gb = Xb + (size_t)gr * 128 + kb * 32 + xu * 4;
            float* lb = sbuf + 4096 + (size_t)(wid * 32 + u * 8) * 32;
            GLOBAL_LOAD_LDS16(gb, lb);
        }
    }
}

template<int DUAL>
static __device__ __forceinline__ void computeK(
    const float* sbuf, const ushort* __restrict__ WaPk, const ushort* __restrict__ WbPk,
    int lane, int wid, int kb, f32x4 (&acc)[2][8])
{
    const int q = lane >> 4, s = lane & 15;
    bf16x8 ah[2], al[2], gh[2], gl[2];
#pragma unroll
    for (int rf = 0; rf < 2; ++rf) {
        int row = wid * 32 + rf * 16 + s;
        int sw = row & 7;
        float4 f0 = *(const float4*)(sbuf + row * 32 + ((2 * q + 0) ^ sw) * 4);
        float4 f1 = *(const float4*)(sbuf + row * 32 + ((2 * q + 1) ^ sw) * 4);
        split8(f0, f1, ah[rf], al[rf]);
        if (DUAL) {
            float4 g0 = *(const float4*)(sbuf + 4096 + row * 32 + ((2 * q + 0) ^ sw) * 4);
            float4 g1 = *(const float4*)(sbuf + 4096 + row * 32 + ((2 * q + 1) ^ sw) * 4);
            split8(g0, g1, gh[rf], gl[rf]);
        }
    }
#pragma unroll
    for (int cf = 0; cf < 8; ++cf) {
        int boff = ((kb * 8 + cf) * 64 + lane) * 8;
        bf16x8 bh = *(const bf16x8*)(WaPk + boff);
        bf16x8 bl = *(const bf16x8*)(WaPk + 16384 + boff);
#pragma unroll
        for (int rf = 0; rf < 2; ++rf) {
            acc[rf][cf] = __builtin_amdgcn_mfma_f32_16x16x32_bf16(ah[rf], bh, acc[rf][cf], 0, 0, 0);
            acc[rf][cf] = __builtin_amdgcn_mfma_f32_16x16x32_bf16(al[rf], bh, acc[rf][cf], 0, 0, 0);
            acc[rf][cf] = __builtin_amdgcn_mfma_f32_16x16x32_bf16(ah[rf], bl, acc[rf][cf], 0, 0, 0);
        }
        if (DUAL) {
            bf16x8 ch = *(const bf16x8*)(WbPk + boff);
            bf16x8 cl = *(const bf16x8*)(WbPk + 16384 + boff);
#pragma unroll
            for (int rf = 0; rf < 2; ++rf) {
                acc[rf][cf] = __builtin_amdgcn_mfma_f32_16x16x32_bf16(gh[rf], ch, acc[rf][cf], 0, 0, 0);
                acc[rf][cf] = __builtin_amdgcn_mfma_f32_16x16x32_bf16(gl[rf], ch, acc[rf][cf], 0, 0, 0);
                acc[rf][cf] = __builtin_amdgcn_mfma_f32_16x16x32_bf16(gh[rf], cl, acc[rf][cf], 0, 0, 0);
            }
        }
    }
}

template<int DUAL, int RELU, int STATS>
__global__ __launch_bounds__(256, 2) void mfma_lin_kernel(
    const float* __restrict__ Xa, const float* __restrict__ Xb,
    const ushort* __restrict__ WaPk, const ushort* __restrict__ WbPk,
    const float* __restrict__ bias, float* __restrict__ Y,
    float* __restrict__ st, int nrows)
{
    __shared__ float sA[2][(DUAL ? 2 : 1) * 4096];   // [buf][input][128 rows x 32 f32]
    __shared__ float sSum[128], sSq[128];
    const int tid  = threadIdx.x;
    const int lane = tid & 63;
    const int wid  = tid >> 6;
    const int q = lane >> 4, s = lane & 15;
    const int rbase0 = blockIdx.x * 128;

    if (STATS) {
        if (tid < 128) sSum[tid] = 0.f;
        else           sSq[tid - 128] = 0.f;
    }

    f32x4 acc[2][8];
#pragma unroll
    for (int rf = 0; rf < 2; ++rf)
#pragma unroll
        for (int cf = 0; cf < 8; ++cf)
            acc[rf][cf] = (f32x4){0.f, 0.f, 0.f, 0.f};

    // double-buffered K pipeline: stage(kb+1) issued before compute(kb); each
    // __syncthreads drains vmcnt -> staged data visible, prev buffer reads done.
    stageA<DUAL>(Xa, Xb, sA[0], rbase0, wid, lane, nrows, 0);
    __syncthreads();
    stageA<DUAL>(Xa, Xb, sA[1], rbase0, wid, lane, nrows, 1);
    computeK<DUAL>(sA[0], WaPk, WbPk, lane, wid, 0, acc);
    __syncthreads();
    stageA<DUAL>(Xa, Xb, sA[0], rbase0, wid, lane, nrows, 2);
    computeK<DUAL>(sA[1], WaPk, WbPk, lane, wid, 1, acc);
    __syncthreads();
    stageA<DUAL>(Xa, Xb, sA[1], rbase0, wid, lane, nrows, 3);
    computeK<DUAL>(sA[0], WaPk, WbPk, lane, wid, 2, acc);
    __syncthreads();
    computeK<DUAL>(sA[1], WaPk, WbPk, lane, wid, 3, acc);

    // epilogue: bias (+relu) + store + fused column stats
#pragma unroll
    for (int cf = 0; cf < 8; ++cf) {
        int colc = cf * 16 + s;
        float bv = bias[colc];
        float cs = 0.f, cq = 0.f;
#pragma unroll
        for (int rf = 0; rf < 2; ++rf) {
            int r0 = rbase0 + wid * 32 + rf * 16 + q * 4;
#pragma unroll
            for (int i = 0; i < 4; ++i) {
                int r = r0 + i;
                float y = acc[rf][cf][i] + bv;
                if (RELU) y = fmaxf(y, 0.f);
                if (r < nrows) {
                    Y[(size_t)r * 128 + colc] = y;
                    if (STATS) { cs += y; cq += y * y; }
                }
            }
        }
        if (STATS) {
            cs += __shfl_xor(cs, 16); cs += __shfl_xor(cs, 32);
            cq += __shfl_xor(cq, 16); cq += __shfl_xor(cq, 32);
            if (q == 0) { atomicAdd(&sSum[colc], cs); atomicAdd(&sSq[colc], cq); }
        }
    }
    if (STATS) {
        __syncthreads();
        if (tid < 128)      atomicAdd(&st[tid], sSum[tid]);
        else if (tid < 256) atomicAdd(&st[tid], sSq[tid - 128]);
    }
}

// ================= BN finalize =================
__global__ void finalize_kernel(float* st, float inv_n) {
    int c = threadIdx.x;
    float mu = st[c] * inv_n;
    float var = st[128 + c] * inv_n - mu * mu;
    st[256 + c] = mu;
    st[384 + c] = rsqrtf(var + EPS);
}

// ================= BN normalize + ReLU (in place) =================
__global__ __launch_bounds__(256) void bnrelu_kernel(
    float* __restrict__ H, const float* __restrict__ st,
    const float* __restrict__ gamma, const float* __restrict__ beta, int n4)
{
    for (int i = blockIdx.x * 256 + threadIdx.x; i < n4; i += gridDim.x * 256) {
        int c4 = i & 31;
        float4 h = ((float4*)H)[i];
        float4 mu = *(const float4*)(st + 256 + c4 * 4);
        float4 rs = *(const float4*)(st + 384 + c4 * 4);
        float4 g  = *(const float4*)(gamma + c4 * 4);
        float4 b  = *(const float4*)(beta + c4 * 4);
        h.x = fmaxf((h.x - mu.x) * rs.x * g.x + b.x, 0.f);
        h.y = fmaxf((h.y - mu.y) * rs.y * g.y + b.y, 0.f);
        h.z = fmaxf((h.z - mu.z) * rs.z * g.z + b.z, 0.f);
        h.w = fmaxf((h.w - mu.w) * rs.w * g.w + b.w, 0.f);
        ((float4*)H)[i] = h;
    }
}

// ================= final projection to DOUT=2 =================
__global__ __launch_bounds__(256) void linout_kernel(
    const float* __restrict__ X, const float* __restrict__ W, const float* __restrict__ b,
    float* __restrict__ out, int nrows)
{
    int r = blockIdx.x * 256 + threadIdx.x;
    if (r >= nrows) return;
    float a0 = 0.f, a1 = 0.f;
    const float* xr = X + (size_t)r * 128;
#pragma unroll 8
    for (int k = 0; k < 128; k += 4) {
        float4 x = *(const float4*)(xr + k);
        a0 += x.x * W[(k + 0) * 2]     + x.y * W[(k + 1) * 2]
            + x.z * W[(k + 2) * 2]     + x.w * W[(k + 3) * 2];
        a1 += x.x * W[(k + 0) * 2 + 1] + x.y * W[(k + 1) * 2 + 1]
            + x.z * W[(k + 2) * 2 + 1] + x.w * W[(k + 3) * 2 + 1];
    }
    float2 o = make_float2(a0 + b[0], a1 + b[1]);
    *(float2*)(out + (size_t)r * 2) = o;
}

extern "C" void kernel_launch(void* const* d_in, const int* in_sizes, int n_in,
                              void* d_out, int out_size, void* d_ws, size_t ws_size,
                              hipStream_t stream) {
    const float* x   = (const float*)d_in[0];
    const int*   ei  = (const int*)d_in[1];
    const float* Wl0 = (const float*)d_in[2];
    const float* bl0 = (const float*)d_in[3];
    const float* Wr0 = (const float*)d_in[4];
    const float* Wl1 = (const float*)d_in[5];
    const float* bl1 = (const float*)d_in[6];
    const float* Wr1 = (const float*)d_in[7];
    const float* g0  = (const float*)d_in[8];
    const float* be0 = (const float*)d_in[9];
    const float* g1  = (const float*)d_in[10];
    const float* be1 = (const float*)d_in[11];
    const float* W1  = (const float*)d_in[12];
    const float* b1  = (const float*)d_in[13];
    const float* W2  = (const float*)d_in[14];
    const float* b2  = (const float*)d_in[15];
    const float* W3  = (const float*)d_in[16];
    const float* b3  = (const float*)d_in[17];
    float* out = (float*)d_out;

    const int N = in_sizes[0] / 128;
    const int E = in_sizes[1] / 2;

    // workspace layout
    float* A  = (float*)d_ws;                    // [N,128]
    float* B  = A + (size_t)N * 128;             // [N,128]
    float* st = B + (size_t)N * 128;             // 512 floats
    ushort* wPk = (ushort*)(st + 512);           // 6 * 32768 (per-matrix [hi|lo])
    int* deg    = (int*)(wPk + 6 * 32768);       // N
    int* rowptr = deg + N;                       // N+1
    int* cursor = rowptr + N + 1;                // N
    int* col    = cursor + N;                    // E
    int* bsum   = col + E;                       // <=512

    const int linGrid    = (N + 127) / 128;
    const int edgeGrid   = (E + 255) / 256;
    const int nodeGrid   = (N + 255) / 256;
    const int gatherGrid = ((size_t)N * 32 + 255) / 256;
    const float inv_n = 1.0f / (float)N;

    // matrix slots: 0=Wl0 1=Wr0 2=Wl1 3=Wr1 4=W1 5=W2
    prepack_kernel<<<dim3(8, 6), 256, 0, stream>>>(Wl0, Wr0, Wl1, Wr1, W1, W2, wPk);

    // ----- CSR build -----
    hipMemsetAsync(deg, 0, (size_t)N * sizeof(int), stream);
    hist_kernel<<<edgeGrid, 256, 0, stream>>>(ei, deg, E);
    blocksum_kernel<<<nodeGrid, 256, 0, stream>>>(deg, bsum, N);
    scanb_kernel<<<1, 512, 0, stream>>>(bsum, nodeGrid);
    scanfinal_kernel<<<nodeGrid, 256, 0, stream>>>(deg, bsum, rowptr, cursor, N);
    fill_kernel<<<edgeGrid, 256, 0, stream>>>(ei, cursor, col, E);

    // ----- layer 0: h0 = agg(x)@Wl0 + x@Wr0 + bl0, fused stats -----
    gather_kernel<<<gatherGrid, 256, 0, stream>>>(x, A, rowptr, col, N);
    hipMemsetAsync(st, 0, 256 * sizeof(float), stream);
    mfma_lin_kernel<1, 0, 1><<<linGrid, 256, 0, stream>>>(
        A, x, wPk, wPk + 32768, bl0, A, st, N);
    finalize_kernel<<<1, 128, 0, stream>>>(st, inv_n);
    bnrelu_kernel<<<2048, 256, 0, stream>>>(A, st, g0, be0, N * 32);

    // ----- layer 1 -----
    gather_kernel<<<gatherGrid, 256, 0, stream>>>(A, B, rowptr, col, N);
    hipMemsetAsync(st, 0, 256 * sizeof(float), stream);
    mfma_lin_kernel<1, 0, 1><<<linGrid, 256, 0, stream>>>(
        B, A, wPk + 2 * 32768, wPk + 3 * 32768, bl1, B, st, N);
    finalize_kernel<<<1, 128, 0, stream>>>(st, inv_n);
    bnrelu_kernel<<<2048, 256, 0, stream>>>(B, st, g1, be1, N * 32);

    // ----- MLP head -----
    mfma_lin_kernel<0, 1, 0><<<linGrid, 256, 0, stream>>>(
        B, nullptr, wPk + 4 * 32768, nullptr, b1, A, nullptr, N);
    mfma_lin_kernel<0, 1, 0><<<linGrid, 256, 0, stream>>>(
        A, nullptr, wPk + 5 * 32768, nullptr, b2, B, nullptr, N);
    linout_kernel<<<(N + 255) / 256, 256, 0, stream>>>(B, W3, b3, out, N);
}